// Round 1
// baseline (246.639 us; speedup 1.0000x reference)
//
#include <hip/hip_runtime.h>

// Problem constants (match reference)
#define BB    8
#define NMAX  128
#define HH    192
#define WW    256

// Antiderivative of the bilinear hat kernel, with clipping.
__device__ __forceinline__ float hatP(float u) {
    u = fminf(fmaxf(u, -1.0f), 1.0f);
    return (u <= 0.0f) ? 0.5f * (u + 1.0f) * (u + 1.0f)
                       : 0.5f + u - 0.5f * u * u;
}

// One block per box. Exploits that axis weights are exactly zero outside
// (lo-1, hi+1): support is <= ~21x21 grid points per box.
__global__ __launch_bounds__(256)
void box_count_kernel(const float* __restrict__ den,    // [B,1,H,W]
                      const float* __restrict__ hboxes, // [B,N,5]
                      const float* __restrict__ post,   // [B,N,H,W]
                      float* __restrict__ err_out,      // [B*N]
                      float* __restrict__ val_out) {    // [B*N]
    const int bn = blockIdx.x;           // b*NMAX + n
    const int b  = bn / NMAX;

    const float* box = hboxes + bn * 5;
    const float x1 = box[0] * 0.125f;
    const float y1 = box[1] * 0.125f;
    const float x2 = box[2] * 0.125f;
    const float y2 = box[3] * 0.125f;
    const float valid = (box[4] > 0.0f) ? 1.0f : 0.0f;

    // Support of the hat-integral weights (zero outside (lo-1, hi+1)).
    const int ix0 = max(0,      (int)ceilf (x1 - 1.0f));
    const int ix1 = min(WW - 1, (int)floorf(x2 + 1.0f));
    const int iy0 = max(0,      (int)ceilf (y1 - 1.0f));
    const int iy1 = min(HH - 1, (int)floorf(y2 + 1.0f));
    const int nx = ix1 - ix0 + 1;        // <= ~21
    const int ny = iy1 - iy0 + 1;        // <= ~21
    const int total = nx * ny;           // <= ~441

    const float* post_bn = post + (size_t)bn * HH * WW;
    const float* den_b   = den  + (size_t)b  * HH * WW;

    float acc = 0.0f;
    for (int t = threadIdx.x; t < total; t += 256) {
        const int iy = iy0 + t / nx;
        const int ix = ix0 + t % nx;
        const float wyv = hatP(y2 - (float)iy) - hatP(y1 - (float)iy);
        const float wxv = hatP(x2 - (float)ix) - hatP(x1 - (float)ix);
        const float d   = den_b  [iy * WW + ix];
        const float p   = post_bn[iy * WW + ix];
        acc += (wyv * wxv) * (d * p);
    }

    // Block reduction: wave64 shuffle, then 4-entry LDS.
    #pragma unroll
    for (int off = 32; off > 0; off >>= 1)
        acc += __shfl_down(acc, off, 64);

    __shared__ float smem[4];
    const int wave = threadIdx.x >> 6;
    const int lane = threadIdx.x & 63;
    if (lane == 0) smem[wave] = acc;
    __syncthreads();
    if (threadIdx.x == 0) {
        const float cnt = smem[0] + smem[1] + smem[2] + smem[3];
        err_out[bn] = fabsf(cnt - 1.0f) * valid;
        val_out[bn] = valid;
    }
}

// Single wave: per-image normalize and sum to the scalar loss.
__global__ __launch_bounds__(64)
void finalize_kernel(const float* __restrict__ err,   // [B*N]
                     const float* __restrict__ val,   // [B*N]
                     float* __restrict__ out) {       // [1]
    const int lane = threadIdx.x;  // 64 threads, one wave
    float total = 0.0f;
    for (int b = 0; b < BB; ++b) {
        float e = err[b * NMAX + lane] + err[b * NMAX + lane + 64];
        float v = val[b * NMAX + lane] + val[b * NMAX + lane + 64];
        #pragma unroll
        for (int off = 32; off > 0; off >>= 1) {
            e += __shfl_down(e, off, 64);
            v += __shfl_down(v, off, 64);
        }
        if (lane == 0 && v > 0.0f) total += e / v;
    }
    if (lane == 0) out[0] = total;
}

extern "C" void kernel_launch(void* const* d_in, const int* in_sizes, int n_in,
                              void* d_out, int out_size, void* d_ws, size_t ws_size,
                              hipStream_t stream) {
    // Input order: cls_preds(0) reg_preds(1) off_preds(2) den_preds(3)
    //              fboxes(4) hboxes(5) ctr_masks(6) post_probs(7)
    const float* den    = (const float*)d_in[3];
    const float* hboxes = (const float*)d_in[5];
    const float* post   = (const float*)d_in[7];
    float* out = (float*)d_out;

    float* err_ws = (float*)d_ws;                 // [B*N]
    float* val_ws = err_ws + BB * NMAX;           // [B*N]

    box_count_kernel<<<BB * NMAX, 256, 0, stream>>>(den, hboxes, post,
                                                    err_ws, val_ws);
    finalize_kernel<<<1, 64, 0, stream>>>(err_ws, val_ws, out);
}